// Round 13
// baseline (366.646 us; speedup 1.0000x reference)
//
#include <hip/hip_runtime.h>
#include <hip/hip_bf16.h>

#define NN 20000
#define EE 320000
#define IN 128
#define HID 64
#define OUTC 128
#define NH 3
#define NEG 0.15f
#define IN2 320
#define HO1 192   // NH*HID
#define HO2 384   // NH*OUTC
#define NB_SCAN 79  // ceil(NN/256)
#define GRIDM 313   // ceil(NN/64)

typedef __hip_bfloat16 bf16;
typedef __attribute__((ext_vector_type(8))) short short8;  // 8 bf16 = 4 VGPR (MFMA A/B frag)
typedef __attribute__((ext_vector_type(4))) float f32x4;   // MFMA C/D frag

__device__ __forceinline__ float bf2f(bf16 v) { return __bfloat162float(v); }
__device__ __forceinline__ bf16 f2bf(float v) { return __float2bfloat16(v); }
__device__ __forceinline__ float lrelu(float s) { return s > 0.f ? s : NEG * s; }
__device__ __forceinline__ float b2f(unsigned short u) {
    union { unsigned int i; float f; } c; c.i = ((unsigned int)u) << 16; return c.f;
}
__device__ __forceinline__ float b2f_lo(unsigned int d) { return b2f((unsigned short)(d & 0xffffu)); }
__device__ __forceinline__ float b2f_hi(unsigned int d) { return b2f((unsigned short)(d >> 16)); }

// ---------------- CSR build (by dst) — proven rounds 4..12 ----------------
__global__ void k_count(const int* __restrict__ ei, int* __restrict__ cnt) {
    const int e = blockIdx.x * 256 + threadIdx.x;
    if (e < EE) atomicAdd(&cnt[ei[EE + e]], 1);
}

__global__ void k_scanA(const int* __restrict__ cnt, int* __restrict__ loc,
                        int* __restrict__ bsum) {
    __shared__ int sh[256];
    const int t = threadIdx.x;
    const int i = blockIdx.x * 256 + t;
    const int v = (i < NN) ? cnt[i] : 0;
    sh[t] = v; __syncthreads();
    for (int off = 1; off < 256; off <<= 1) {
        const int add = (t >= off) ? sh[t - off] : 0;
        __syncthreads();
        sh[t] += add; __syncthreads();
    }
    if (i < NN) loc[i] = sh[t];
    if (t == 255) bsum[blockIdx.x] = sh[255];
}

__global__ void k_scanB(int* __restrict__ bsum) {
    __shared__ int sh[128];
    const int t = threadIdx.x;
    const int v = (t < NB_SCAN) ? bsum[t] : 0;
    sh[t] = v; __syncthreads();
    for (int off = 1; off < 128; off <<= 1) {
        const int add = (t >= off) ? sh[t - off] : 0;
        __syncthreads();
        sh[t] += add; __syncthreads();
    }
    if (t < NB_SCAN) bsum[t] = sh[t] - v;
}

__global__ void k_scanC(const int* __restrict__ loc, const int* __restrict__ cnt,
                        const int* __restrict__ bsum, int* __restrict__ row_off,
                        int* __restrict__ fill) {
    const int i = blockIdx.x * 256 + threadIdx.x;
    if (i < NN) {
        const int ro = loc[i] - cnt[i] + bsum[blockIdx.x];
        row_off[i] = ro; fill[i] = ro;
    }
    if (i == 0) row_off[NN] = EE;
}

__global__ void k_scatter(const int* __restrict__ ei, int* __restrict__ fill,
                          int* __restrict__ csr_src) {
    const int e = blockIdx.x * 256 + threadIdx.x;
    if (e < EE) {
        const int p = atomicAdd(&fill[ei[EE + e]], 1);
        csr_src[p] = ei[e];
    }
}

// ---------------- pre-pass: bf16 casts / weight transpose ----------------
__global__ void k_a2x(const float* __restrict__ x, bf16* __restrict__ xb) {
    const int idx = blockIdx.x * 256 + threadIdx.x;
    if (idx < NN * IN) xb[idx] = f2bf(x[idx]);
}

// Wt[n][k] = bf16( n<NO ? Wl[k][n] : Wr[k][n-NO] ), Wl/Wr [K,NO] row stride NO
__global__ void k_wt(const float* __restrict__ Wl, const float* __restrict__ Wr,
                     int K, int NO, bf16* __restrict__ Wt) {
    const int idx = blockIdx.x * 256 + threadIdx.x;
    if (idx >= 2 * NO * K) return;
    const int n = idx / K, k = idx - n * K;
    const float* W = (n < NO) ? Wl : Wr;
    const int nn = (n < NO) ? n : n - NO;
    Wt[idx] = f2bf(W[(size_t)k * NO + nn]);
}

// ---------------- MFMA GEMM: 32x64/wave, prefetch; PER-HEAD PLANAR epilogue ----
// Output: o[h*planeN + row*CH + c]   where col = h*CH + c within l/r half.
template <int K, int CH>
__launch_bounds__(256)
__global__ void gemm_mfma(const bf16* __restrict__ A0, int As0,   // k < 128
                          const bf16* __restrict__ A1, int As1,   // k >= 128 (index k-128)
                          const bf16* __restrict__ Wt,
                          const float* __restrict__ bl, const float* __restrict__ br,
                          int NO, size_t planeN,
                          bf16* __restrict__ outl, bf16* __restrict__ outr) {
    const int w = threadIdx.x >> 6;
    const int lane = threadIdx.x & 63;
    const int quad = lane >> 4, l15 = lane & 15;
    const int m0 = blockIdx.x * 64 + (w >> 1) * 32;
    const int n0 = blockIdx.y * 128 + (w & 1) * 64;

    int am0 = m0 + l15;      if (am0 >= NN) am0 = NN - 1;   // clamp: loads stay in ws
    int am1 = m0 + 16 + l15; if (am1 >= NN) am1 = NN - 1;
    const bf16* wp = Wt + (size_t)(n0 + l15) * K + quad * 8;

    f32x4 acc[2][4];
#pragma unroll
    for (int nt = 0; nt < 4; ++nt) {
        const int col = n0 + nt * 16 + l15;
        const float b = (col < NO) ? bl[col] : br[col - NO];
        acc[0][nt] = (f32x4){b, b, b, b};
        acc[1][nt] = (f32x4){b, b, b, b};
    }

    short8 ca0, ca1, cb[4];
    {
        ca0 = *(const short8*)(A0 + (size_t)am0 * As0 + quad * 8);
        ca1 = *(const short8*)(A0 + (size_t)am1 * As0 + quad * 8);
#pragma unroll
        for (int nt = 0; nt < 4; ++nt)
            cb[nt] = *(const short8*)(wp + (size_t)nt * 16 * K);
    }

#pragma unroll
    for (int ks = 0; ks < K; ks += 32) {
        short8 na0 = {}, na1 = {}, nb[4] = {};
        if (ks + 32 < K) {
            const int nks = ks + 32;
            const bf16* a0p = (K <= 128 || nks < 128)
                ? (A0 + (size_t)am0 * As0 + nks) : (A1 + (size_t)am0 * As1 + (nks - 128));
            const bf16* a1p = (K <= 128 || nks < 128)
                ? (A0 + (size_t)am1 * As0 + nks) : (A1 + (size_t)am1 * As1 + (nks - 128));
            na0 = *(const short8*)(a0p + quad * 8);
            na1 = *(const short8*)(a1p + quad * 8);
#pragma unroll
            for (int nt = 0; nt < 4; ++nt)
                nb[nt] = *(const short8*)(wp + (size_t)nt * 16 * K + nks);
        }
#pragma unroll
        for (int nt = 0; nt < 4; ++nt) {
            acc[0][nt] = __builtin_amdgcn_mfma_f32_16x16x32_bf16(ca0, cb[nt], acc[0][nt], 0, 0, 0);
            acc[1][nt] = __builtin_amdgcn_mfma_f32_16x16x32_bf16(ca1, cb[nt], acc[1][nt], 0, 0, 0);
        }
        ca0 = na0; ca1 = na1;
#pragma unroll
        for (int nt = 0; nt < 4; ++nt) cb[nt] = nb[nt];
    }

#pragma unroll
    for (int mt = 0; mt < 2; ++mt)
#pragma unroll
    for (int nt = 0; nt < 4; ++nt) {
        const int col = n0 + nt * 16 + l15;
        const int cc = (col < NO) ? col : col - NO;
        bf16* o = (col < NO) ? outl : outr;
        const int h = cc / CH, c = cc - h * CH;
#pragma unroll
        for (int r = 0; r < 4; ++r) {
            const int row = m0 + mt * 16 + quad * 4 + r;
            if (row < NN) o[h * planeN + (size_t)row * CH + c] = f2bf(acc[mt][nt][r]);
        }
    }
}

// ---------------- gather1: BLOCK(192)=3 waves per dst, wave=head ----------------
// xl/xr planar [h][N][64] bf16; lane = channel -> 1 ushort/edge, 128B coalesced.
__global__ void gather1(const int* __restrict__ row_off, const int* __restrict__ csr_src,
                        const bf16* __restrict__ xl, const bf16* __restrict__ xr,
                        const float* __restrict__ att, const float* __restrict__ bias,
                        bf16* __restrict__ h1) {
    const int i = blockIdx.x;
    const int w = threadIdx.x >> 6;      // head
    const int lane = threadIdx.x & 63;   // channel
    const unsigned short* xlu = (const unsigned short*)xl + (size_t)w * NN * HID;
    const unsigned short* xru = (const unsigned short*)xr + (size_t)w * NN * HID;
    const float rv = b2f(xru[(size_t)i * HID + lane]);
    const float av = att[w * HID + lane];
    int k = row_off[i];
    const int e = row_off[i + 1];
    float a = 0.f, d = 0.f;
    while (k < e) {
        const int batch = min(64, e - k);
        const int jv = (lane < batch) ? csr_src[k + lane] : 0;
        int m = 0;
        for (; m + 8 <= batch; m += 8) {             // 8 interleaved chains
            float lv[8], p[8];
#pragma unroll
            for (int q = 0; q < 8; ++q) {
                const int j = __shfl(jv, m + q, 64);
                lv[q] = b2f(xlu[(size_t)j * HID + lane]);
                p[q] = lrelu(lv[q] + rv) * av;
            }
#pragma unroll
            for (int off = 32; off > 0; off >>= 1)
#pragma unroll
                for (int q = 0; q < 8; ++q) p[q] += __shfl_xor(p[q], off, 64);
#pragma unroll
            for (int q = 0; q < 8; ++q) {
                const float ex = __expf(p[q]);
                a += ex * lv[q]; d += ex;
            }
        }
        for (; m < batch; ++m) {
            const int j = __shfl(jv, m, 64);
            const float lv = b2f(xlu[(size_t)j * HID + lane]);
            float p = lrelu(lv + rv) * av;
#pragma unroll
            for (int off = 32; off > 0; off >>= 1) p += __shfl_xor(p, off, 64);
            const float ex = __expf(p);
            a += ex * lv; d += ex;
        }
        k += batch;
    }
    __shared__ float part[NH][HID];
    part[w][lane] = a / (d + 1e-16f);
    __syncthreads();
    const int o = threadIdx.x;           // 0..191
    const float v = part[o >> 6][o & 63] + bias[o];
    h1[(size_t)i * HO1 + o] = f2bf(v > 0.f ? v : 0.f);
}

// ---------------- gather2: BLOCK(192)=3 waves per dst, wave=head ----------------
// xl2/xr2 planar [h][N][128] bf16; lane = channels 2l,2l+1 -> 1 dword/edge, 256B coalesced.
__global__ void gather2(const int* __restrict__ row_off, const int* __restrict__ csr_src,
                        const bf16* __restrict__ xl2, const bf16* __restrict__ xr2,
                        const float* __restrict__ att2, const float* __restrict__ bias2,
                        float* __restrict__ out) {
    const int i = blockIdx.x;
    const int w = threadIdx.x >> 6;      // head
    const int lane = threadIdx.x & 63;   // channel pair
    const unsigned int* xlw = (const unsigned int*)xl2 + (size_t)w * NN * (OUTC / 2);
    const unsigned int* xrw = (const unsigned int*)xr2 + (size_t)w * NN * (OUTC / 2);
    const unsigned int r = xrw[(size_t)i * (OUTC / 2) + lane];
    const float rv0 = b2f_lo(r), rv1 = b2f_hi(r);
    const float2 av = *(const float2*)&att2[w * OUTC + 2 * lane];
    int k = row_off[i];
    const int e = row_off[i + 1];
    float a0 = 0.f, a1 = 0.f, den = 0.f;
    while (k < e) {
        const int batch = min(64, e - k);
        const int jv = (lane < batch) ? csr_src[k + lane] : 0;
        int m = 0;
        for (; m + 8 <= batch; m += 8) {             // 8 interleaved chains
            float l0[8], l1[8], p[8];
#pragma unroll
            for (int q = 0; q < 8; ++q) {
                const int j = __shfl(jv, m + q, 64);
                const unsigned int dw = xlw[(size_t)j * (OUTC / 2) + lane];
                l0[q] = b2f_lo(dw); l1[q] = b2f_hi(dw);
                p[q] = lrelu(l0[q] + rv0) * av.x + lrelu(l1[q] + rv1) * av.y;
            }
#pragma unroll
            for (int off = 32; off > 0; off >>= 1)
#pragma unroll
                for (int q = 0; q < 8; ++q) p[q] += __shfl_xor(p[q], off, 64);
#pragma unroll
            for (int q = 0; q < 8; ++q) {
                const float ex = __expf(p[q]);
                a0 += ex * l0[q]; a1 += ex * l1[q]; den += ex;
            }
        }
        for (; m < batch; ++m) {
            const int j = __shfl(jv, m, 64);
            const unsigned int dw = xlw[(size_t)j * (OUTC / 2) + lane];
            const float l0 = b2f_lo(dw), l1 = b2f_hi(dw);
            float p = lrelu(l0 + rv0) * av.x + lrelu(l1 + rv1) * av.y;
#pragma unroll
            for (int off = 32; off > 0; off >>= 1) p += __shfl_xor(p, off, 64);
            const float ex = __expf(p);
            a0 += ex * l0; a1 += ex * l1; den += ex;
        }
        k += batch;
    }
    __shared__ float part[NH][OUTC];
    const float inv = 1.f / (den + 1e-16f);
    part[w][2 * lane] = a0 * inv;
    part[w][2 * lane + 1] = a1 * inv;
    __syncthreads();
    if (threadIdx.x < OUTC) {
        const int c = threadIdx.x;
        float v = (part[0][c] + part[1][c] + part[2][c]) * (1.f / 3.f) + bias2[c];
        out[(size_t)i * OUTC + c] = v > 0.f ? v : 0.f;
    }
}

extern "C" void kernel_launch(void* const* d_in, const int* in_sizes, int n_in,
                              void* d_out, int out_size, void* d_ws, size_t ws_size,
                              hipStream_t stream) {
    const float* x    = (const float*)d_in[0];
    const float* Wl1  = (const float*)d_in[1];
    const float* bl1  = (const float*)d_in[2];
    const float* Wr1  = (const float*)d_in[3];
    const float* br1  = (const float*)d_in[4];
    const float* att1 = (const float*)d_in[5];
    const float* bias1= (const float*)d_in[6];
    const float* Wl2  = (const float*)d_in[7];
    const float* bl2  = (const float*)d_in[8];
    const float* Wr2  = (const float*)d_in[9];
    const float* br2  = (const float*)d_in[10];
    const float* att2 = (const float*)d_in[11];
    const float* bias2= (const float*)d_in[12];
    const int*   ei   = (const int*)d_in[13];

    char* ws = (char*)d_ws;
    // Pool layout (bytes), peak 45,713,936 — identical footprint to proven rounds 10-12:
    //  [0,         5,120,000)  xb   bf16 [N,128]
    //  [5.12e6,   12,800,000)  h1b  bf16 [N,192]
    //  [12.8e6,   20,480,000)  xl1 planar [3][N][64]  \ dead after gather1 ->
    //  [20.48e6,  28,160,000)  xr1 planar [3][N][64]  /  xl2 planar [3][N][128] = [12.8e6, 28.16e6)
    //  [28.16e6,  43,520,000)  xr2 planar [3][N][128]
    //  [43.52e6,  45,124,104)  CSR: cnt/fill/loc/bsum/rowoff/csrsrc
    //  [45,124,112, 45,222,416)  Wt1 bf16 [384][128]
    //  [45,222,416, 45,713,936)  Wt2 bf16 [768][320]
    bf16*  xb     = (bf16*)(ws);
    bf16*  h1b    = (bf16*)(ws + 5120000);
    bf16*  xl1    = (bf16*)(ws + 12800000);
    bf16*  xr1    = (bf16*)(ws + 20480000);
    bf16*  xl2    = (bf16*)(ws + 12800000);   // alias: xl1/xr1 dead after gather1
    bf16*  xr2    = (bf16*)(ws + 28160000);
    int*   cnt    = (int*)(ws + 43520000);
    int*   fill   = (int*)(ws + 43600000);
    int*   loc    = (int*)(ws + 43680000);
    int*   bsum   = (int*)(ws + 43760000);
    int*   rowoff = (int*)(ws + 43764096);
    int*   csrsrc = (int*)(ws + 43844104);    // +1,280,000 -> 45,124,104
    bf16*  Wt1    = (bf16*)(ws + 45124112);
    bf16*  Wt2    = (bf16*)(ws + 45222416);

    // ---- pre-pass: casts + weight transposes ----
    k_a2x<<<(NN * IN + 255) / 256, 256, 0, stream>>>(x, xb);
    k_wt<<<(HO2 * IN + 255) / 256, 256, 0, stream>>>(Wl1, Wr1, IN, HO1, Wt1);      // 384x128
    k_wt<<<(2 * HO2 * IN2 + 255) / 256, 256, 0, stream>>>(Wl2, Wr2, IN2, HO2, Wt2); // 768x320

    // ---- CSR build (shared by both layers) ----
    hipMemsetAsync(cnt, 0, NN * sizeof(int), stream);
    k_count<<<(EE + 255) / 256, 256, 0, stream>>>(ei, cnt);
    k_scanA<<<NB_SCAN, 256, 0, stream>>>(cnt, loc, bsum);
    k_scanB<<<1, 128, 0, stream>>>(bsum);
    k_scanC<<<NB_SCAN, 256, 0, stream>>>(loc, cnt, bsum, rowoff, fill);
    k_scatter<<<(EE + 255) / 256, 256, 0, stream>>>(ei, fill, csrsrc);

    // ---- layer 1 ----
    gemm_mfma<IN, HID><<<dim3(GRIDM, HO2 / 128), 256, 0, stream>>>(
        xb, IN, (const bf16*)nullptr, 0, Wt1, bl1, br1, HO1,
        (size_t)NN * HID, xl1, xr1);
    gather1<<<NN, 192, 0, stream>>>(rowoff, csrsrc, xl1, xr1, att1, bias1, h1b);

    // ---- layer 2 ----
    gemm_mfma<IN2, OUTC><<<dim3(GRIDM, 2 * HO2 / 128), 256, 0, stream>>>(
        xb, IN, h1b, HO1, Wt2, bl2, br2, HO2,
        (size_t)NN * OUTC, xl2, xr2);
    gather2<<<NN, 192, 0, stream>>>(rowoff, csrsrc, xl2, xr2, att2, bias2,
                                    (float*)d_out);
}

// Round 14
// 292.063 us; speedup vs baseline: 1.2554x; 1.2554x over previous
//
#include <hip/hip_runtime.h>
#include <hip/hip_bf16.h>

#define NN 20000
#define EE 320000
#define IN 128
#define HID 64
#define OUTC 128
#define NH 3
#define NEG 0.15f
#define IN2 320
#define HO1 192   // NH*HID
#define HO2 384   // NH*OUTC
#define NB_SCAN 79  // ceil(NN/256)
#define GRIDM 313   // ceil(NN/64)

typedef __hip_bfloat16 bf16;
typedef __attribute__((ext_vector_type(8))) short short8;  // 8 bf16 = 4 VGPR
typedef __attribute__((ext_vector_type(4))) float f32x4;   // MFMA C/D frag

__device__ __forceinline__ float bf2f(bf16 v) { return __bfloat162float(v); }
__device__ __forceinline__ bf16 f2bf(float v) { return __float2bfloat16(v); }
__device__ __forceinline__ float lrelu(float s) { return s > 0.f ? s : NEG * s; }
__device__ __forceinline__ float b2f(unsigned short u) {
    union { unsigned int i; float f; } c; c.i = ((unsigned int)u) << 16; return c.f;
}

// ---------------- CSR build (by dst) — proven rounds 4..13 ----------------
__global__ void k_count(const int* __restrict__ ei, int* __restrict__ cnt) {
    const int e = blockIdx.x * 256 + threadIdx.x;
    if (e < EE) atomicAdd(&cnt[ei[EE + e]], 1);
}

__global__ void k_scanA(const int* __restrict__ cnt, int* __restrict__ loc,
                        int* __restrict__ bsum) {
    __shared__ int sh[256];
    const int t = threadIdx.x;
    const int i = blockIdx.x * 256 + t;
    const int v = (i < NN) ? cnt[i] : 0;
    sh[t] = v; __syncthreads();
    for (int off = 1; off < 256; off <<= 1) {
        const int add = (t >= off) ? sh[t - off] : 0;
        __syncthreads();
        sh[t] += add; __syncthreads();
    }
    if (i < NN) loc[i] = sh[t];
    if (t == 255) bsum[blockIdx.x] = sh[255];
}

__global__ void k_scanB(int* __restrict__ bsum) {
    __shared__ int sh[128];
    const int t = threadIdx.x;
    const int v = (t < NB_SCAN) ? bsum[t] : 0;
    sh[t] = v; __syncthreads();
    for (int off = 1; off < 128; off <<= 1) {
        const int add = (t >= off) ? sh[t - off] : 0;
        __syncthreads();
        sh[t] += add; __syncthreads();
    }
    if (t < NB_SCAN) bsum[t] = sh[t] - v;
}

__global__ void k_scanC(const int* __restrict__ loc, const int* __restrict__ cnt,
                        const int* __restrict__ bsum, int* __restrict__ row_off,
                        int* __restrict__ fill) {
    const int i = blockIdx.x * 256 + threadIdx.x;
    if (i < NN) {
        const int ro = loc[i] - cnt[i] + bsum[blockIdx.x];
        row_off[i] = ro; fill[i] = ro;
    }
    if (i == 0) row_off[NN] = EE;
}

__global__ void k_scatter(const int* __restrict__ ei, int* __restrict__ fill,
                          int* __restrict__ csr_src) {
    const int e = blockIdx.x * 256 + threadIdx.x;
    if (e < EE) {
        const int p = atomicAdd(&fill[ei[EE + e]], 1);
        csr_src[p] = ei[e];
    }
}

// ---------------- pre-pass: bf16 casts / weight transpose ----------------
__global__ void k_a2x(const float* __restrict__ x, bf16* __restrict__ xb) {
    const int idx = blockIdx.x * 256 + threadIdx.x;
    if (idx < NN * IN) xb[idx] = f2bf(x[idx]);
}

__global__ void k_wt(const float* __restrict__ Wl, const float* __restrict__ Wr,
                     int K, int NO, bf16* __restrict__ Wt) {
    const int idx = blockIdx.x * 256 + threadIdx.x;
    if (idx >= 2 * NO * K) return;
    const int n = idx / K, k = idx - n * K;
    const float* W = (n < NO) ? Wl : Wr;
    const int nn = (n < NO) ? n : n - NO;
    Wt[idx] = f2bf(W[(size_t)k * NO + nn]);
}

// ---------------- MFMA GEMM: 32x64/wave, prefetch; per-head planar epilogue ----
template <int K, int CH>
__launch_bounds__(256)
__global__ void gemm_mfma(const bf16* __restrict__ A0, int As0,   // k < 128
                          const bf16* __restrict__ A1, int As1,   // k >= 128
                          const bf16* __restrict__ Wt,
                          const float* __restrict__ bl, const float* __restrict__ br,
                          int NO, size_t planeN,
                          bf16* __restrict__ outl, bf16* __restrict__ outr) {
    const int w = threadIdx.x >> 6;
    const int lane = threadIdx.x & 63;
    const int quad = lane >> 4, l15 = lane & 15;
    const int m0 = blockIdx.x * 64 + (w >> 1) * 32;
    const int n0 = blockIdx.y * 128 + (w & 1) * 64;

    int am0 = m0 + l15;      if (am0 >= NN) am0 = NN - 1;
    int am1 = m0 + 16 + l15; if (am1 >= NN) am1 = NN - 1;
    const bf16* wp = Wt + (size_t)(n0 + l15) * K + quad * 8;

    f32x4 acc[2][4];
#pragma unroll
    for (int nt = 0; nt < 4; ++nt) {
        const int col = n0 + nt * 16 + l15;
        const float b = (col < NO) ? bl[col] : br[col - NO];
        acc[0][nt] = (f32x4){b, b, b, b};
        acc[1][nt] = (f32x4){b, b, b, b};
    }

    short8 ca0, ca1, cb[4];
    {
        ca0 = *(const short8*)(A0 + (size_t)am0 * As0 + quad * 8);
        ca1 = *(const short8*)(A0 + (size_t)am1 * As0 + quad * 8);
#pragma unroll
        for (int nt = 0; nt < 4; ++nt)
            cb[nt] = *(const short8*)(wp + (size_t)nt * 16 * K);
    }

#pragma unroll
    for (int ks = 0; ks < K; ks += 32) {
        short8 na0 = {}, na1 = {}, nb[4] = {};
        if (ks + 32 < K) {
            const int nks = ks + 32;
            const bf16* a0p = (K <= 128 || nks < 128)
                ? (A0 + (size_t)am0 * As0 + nks) : (A1 + (size_t)am0 * As1 + (nks - 128));
            const bf16* a1p = (K <= 128 || nks < 128)
                ? (A0 + (size_t)am1 * As0 + nks) : (A1 + (size_t)am1 * As1 + (nks - 128));
            na0 = *(const short8*)(a0p + quad * 8);
            na1 = *(const short8*)(a1p + quad * 8);
#pragma unroll
            for (int nt = 0; nt < 4; ++nt)
                nb[nt] = *(const short8*)(wp + (size_t)nt * 16 * K + nks);
        }
#pragma unroll
        for (int nt = 0; nt < 4; ++nt) {
            acc[0][nt] = __builtin_amdgcn_mfma_f32_16x16x32_bf16(ca0, cb[nt], acc[0][nt], 0, 0, 0);
            acc[1][nt] = __builtin_amdgcn_mfma_f32_16x16x32_bf16(ca1, cb[nt], acc[1][nt], 0, 0, 0);
        }
        ca0 = na0; ca1 = na1;
#pragma unroll
        for (int nt = 0; nt < 4; ++nt) cb[nt] = nb[nt];
    }

#pragma unroll
    for (int mt = 0; mt < 2; ++mt)
#pragma unroll
    for (int nt = 0; nt < 4; ++nt) {
        const int col = n0 + nt * 16 + l15;
        const int cc = (col < NO) ? col : col - NO;
        bf16* o = (col < NO) ? outl : outr;
        const int h = cc / CH, c = cc - h * CH;
#pragma unroll
        for (int r = 0; r < 4; ++r) {
            const int row = m0 + mt * 16 + quad * 4 + r;
            if (row < NN) o[h * planeN + (size_t)row * CH + c] = f2bf(acc[mt][nt][r]);
        }
    }
}

// ---------------- gather1: block(192)=3 head-waves; 8-LANE GROUP PER EDGE -------
// planar [h][N][64]; lane t=lane&7 holds channels 8t..8t+7 (dwordx4). 8 edges/wave-iter.
// Butterfly: 3 stages within group (vs 6 across wave). Group partials -> LDS.
__global__ void gather1(const int* __restrict__ row_off, const int* __restrict__ csr_src,
                        const bf16* __restrict__ xl, const bf16* __restrict__ xr,
                        const float* __restrict__ att, const float* __restrict__ bias,
                        bf16* __restrict__ h1) {
    const int i = blockIdx.x;
    const int w = threadIdx.x >> 6;      // head
    const int lane = threadIdx.x & 63;
    const int g = lane >> 3;             // group 0..7 (edge slot)
    const int t = lane & 7;              // channels 8t..8t+7
    const unsigned short* xlu = (const unsigned short*)xl + (size_t)w * NN * HID;
    const unsigned short* xru = (const unsigned short*)xr + (size_t)w * NN * HID;
    float rv[8], av[8];
    {
        const short8 ru = *(const short8*)(xru + (size_t)i * HID + 8 * t);
#pragma unroll
        for (int c = 0; c < 8; ++c) {
            rv[c] = b2f((unsigned short)ru[c]);
            av[c] = att[w * HID + 8 * t + c];
        }
    }
    float acc[8] = {0.f, 0.f, 0.f, 0.f, 0.f, 0.f, 0.f, 0.f};
    float den = 0.f;
    const int kb = row_off[i], ke = row_off[i + 1];
    for (int p0 = kb; p0 < ke; p0 += 8) {
        const int idx = p0 + g;
        const int j = csr_src[idx < ke ? idx : ke - 1];   // 8 dwords, 1 line, L1-hot
        const short8 lu = *(const short8*)(xlu + (size_t)j * HID + 8 * t);
        float lv[8], p = 0.f;
#pragma unroll
        for (int c = 0; c < 8; ++c) {
            lv[c] = b2f((unsigned short)lu[c]);
            p += lrelu(lv[c] + rv[c]) * av[c];
        }
        p += __shfl_xor(p, 1, 64);
        p += __shfl_xor(p, 2, 64);
        p += __shfl_xor(p, 4, 64);
        const float ex = (idx < ke) ? __expf(p) : 0.f;    // |logit|<~8: fp32-safe
#pragma unroll
        for (int c = 0; c < 8; ++c) acc[c] += ex * lv[c];
        den += ex;
    }
    __shared__ float part[NH][8][HID];   // 6144 B
    __shared__ float dsh[NH][8];
    *(f32x4*)&part[w][g][8 * t]     = (f32x4){acc[0], acc[1], acc[2], acc[3]};
    *(f32x4*)&part[w][g][8 * t + 4] = (f32x4){acc[4], acc[5], acc[6], acc[7]};
    if (t == 0) dsh[w][g] = den;
    __syncthreads();
    const int o = threadIdx.x;           // 0..191 = h*64+c
    const int hh = o >> 6, c = o & 63;
    float num = 0.f, dd = 0.f;
#pragma unroll
    for (int q = 0; q < 8; ++q) { num += part[hh][q][c]; dd += dsh[hh][q]; }
    const float v = num / (dd + 1e-16f) + bias[o];
    h1[(size_t)i * HO1 + o] = f2bf(v > 0.f ? v : 0.f);
}

// ---------------- gather2: block(192)=3 head-waves; 16-LANE GROUP PER EDGE ------
// planar [h][N][128]; lane t=lane&15 holds channels 8t..8t+7 (dwordx4). 4 edges/wave-iter.
__global__ void gather2(const int* __restrict__ row_off, const int* __restrict__ csr_src,
                        const bf16* __restrict__ xl2, const bf16* __restrict__ xr2,
                        const float* __restrict__ att2, const float* __restrict__ bias2,
                        float* __restrict__ out) {
    const int i = blockIdx.x;
    const int w = threadIdx.x >> 6;      // head
    const int lane = threadIdx.x & 63;
    const int g = lane >> 4;             // group 0..3 (edge slot)
    const int t = lane & 15;             // channels 8t..8t+7
    const unsigned short* xlu = (const unsigned short*)xl2 + (size_t)w * NN * OUTC;
    const unsigned short* xru = (const unsigned short*)xr2 + (size_t)w * NN * OUTC;
    float rv[8], av[8];
    {
        const short8 ru = *(const short8*)(xru + (size_t)i * OUTC + 8 * t);
#pragma unroll
        for (int c = 0; c < 8; ++c) {
            rv[c] = b2f((unsigned short)ru[c]);
            av[c] = att2[w * OUTC + 8 * t + c];
        }
    }
    float acc[8] = {0.f, 0.f, 0.f, 0.f, 0.f, 0.f, 0.f, 0.f};
    float den = 0.f;
    const int kb = row_off[i], ke = row_off[i + 1];
    for (int p0 = kb; p0 < ke; p0 += 4) {
        const int idx = p0 + g;
        const int j = csr_src[idx < ke ? idx : ke - 1];   // 4 dwords, 1 line, L1-hot
        const short8 lu = *(const short8*)(xlu + (size_t)j * OUTC + 8 * t);
        float lv[8], p = 0.f;
#pragma unroll
        for (int c = 0; c < 8; ++c) {
            lv[c] = b2f((unsigned short)lu[c]);
            p += lrelu(lv[c] + rv[c]) * av[c];
        }
        p += __shfl_xor(p, 1, 64);
        p += __shfl_xor(p, 2, 64);
        p += __shfl_xor(p, 4, 64);
        p += __shfl_xor(p, 8, 64);
        const float ex = (idx < ke) ? __expf(p) : 0.f;
#pragma unroll
        for (int c = 0; c < 8; ++c) acc[c] += ex * lv[c];
        den += ex;
    }
    __shared__ float part[NH][4][OUTC];  // 6144 B
    __shared__ float dsh[NH][4];
    *(f32x4*)&part[w][g][8 * t]     = (f32x4){acc[0], acc[1], acc[2], acc[3]};
    *(f32x4*)&part[w][g][8 * t + 4] = (f32x4){acc[4], acc[5], acc[6], acc[7]};
    if (t == 0) dsh[w][g] = den;
    __syncthreads();
    if (threadIdx.x < OUTC) {
        const int c = threadIdx.x;
        float v = 0.f;
#pragma unroll
        for (int hh = 0; hh < NH; ++hh) {
            float num = part[hh][0][c] + part[hh][1][c] + part[hh][2][c] + part[hh][3][c];
            float dd  = dsh[hh][0] + dsh[hh][1] + dsh[hh][2] + dsh[hh][3];
            v += num / (dd + 1e-16f);
        }
        v = v * (1.f / 3.f) + bias2[c];
        out[(size_t)i * OUTC + c] = v > 0.f ? v : 0.f;
    }
}

extern "C" void kernel_launch(void* const* d_in, const int* in_sizes, int n_in,
                              void* d_out, int out_size, void* d_ws, size_t ws_size,
                              hipStream_t stream) {
    const float* x    = (const float*)d_in[0];
    const float* Wl1  = (const float*)d_in[1];
    const float* bl1  = (const float*)d_in[2];
    const float* Wr1  = (const float*)d_in[3];
    const float* br1  = (const float*)d_in[4];
    const float* att1 = (const float*)d_in[5];
    const float* bias1= (const float*)d_in[6];
    const float* Wl2  = (const float*)d_in[7];
    const float* bl2  = (const float*)d_in[8];
    const float* Wr2  = (const float*)d_in[9];
    const float* br2  = (const float*)d_in[10];
    const float* att2 = (const float*)d_in[11];
    const float* bias2= (const float*)d_in[12];
    const int*   ei   = (const int*)d_in[13];

    char* ws = (char*)d_ws;
    // Pool layout (bytes), peak 45,713,936 — byte-identical to proven rounds 10-13:
    //  [0,         5,120,000)  xb   bf16 [N,128]
    //  [5.12e6,   12,800,000)  h1b  bf16 [N,192]
    //  [12.8e6,   20,480,000)  xl1 planar [3][N][64]  \ dead after gather1 ->
    //  [20.48e6,  28,160,000)  xr1 planar [3][N][64]  /  xl2 planar [3][N][128]
    //  [28.16e6,  43,520,000)  xr2 planar [3][N][128]
    //  [43.52e6,  45,124,104)  CSR: cnt/fill/loc/bsum/rowoff/csrsrc
    //  [45,124,112, 45,222,416)  Wt1 bf16 [384][128]
    //  [45,222,416, 45,713,936)  Wt2 bf16 [768][320]
    bf16*  xb     = (bf16*)(ws);
    bf16*  h1b    = (bf16*)(ws + 5120000);
    bf16*  xl1    = (bf16*)(ws + 12800000);
    bf16*  xr1    = (bf16*)(ws + 20480000);
    bf16*  xl2    = (bf16*)(ws + 12800000);   // alias: xl1/xr1 dead after gather1
    bf16*  xr2    = (bf16*)(ws + 28160000);
    int*   cnt    = (int*)(ws + 43520000);
    int*   fill   = (int*)(ws + 43600000);
    int*   loc    = (int*)(ws + 43680000);
    int*   bsum   = (int*)(ws + 43760000);
    int*   rowoff = (int*)(ws + 43764096);
    int*   csrsrc = (int*)(ws + 43844104);
    bf16*  Wt1    = (bf16*)(ws + 45124112);
    bf16*  Wt2    = (bf16*)(ws + 45222416);

    // ---- pre-pass: casts + weight transposes ----
    k_a2x<<<(NN * IN + 255) / 256, 256, 0, stream>>>(x, xb);
    k_wt<<<(HO2 * IN + 255) / 256, 256, 0, stream>>>(Wl1, Wr1, IN, HO1, Wt1);
    k_wt<<<(2 * HO2 * IN2 + 255) / 256, 256, 0, stream>>>(Wl2, Wr2, IN2, HO2, Wt2);

    // ---- CSR build ----
    hipMemsetAsync(cnt, 0, NN * sizeof(int), stream);
    k_count<<<(EE + 255) / 256, 256, 0, stream>>>(ei, cnt);
    k_scanA<<<NB_SCAN, 256, 0, stream>>>(cnt, loc, bsum);
    k_scanB<<<1, 128, 0, stream>>>(bsum);
    k_scanC<<<NB_SCAN, 256, 0, stream>>>(loc, cnt, bsum, rowoff, fill);
    k_scatter<<<(EE + 255) / 256, 256, 0, stream>>>(ei, fill, csrsrc);

    // ---- layer 1 ----
    gemm_mfma<IN, HID><<<dim3(GRIDM, HO2 / 128), 256, 0, stream>>>(
        xb, IN, (const bf16*)nullptr, 0, Wt1, bl1, br1, HO1,
        (size_t)NN * HID, xl1, xr1);
    gather1<<<NN, 192, 0, stream>>>(rowoff, csrsrc, xl1, xr1, att1, bias1, h1b);

    // ---- layer 2 ----
    gemm_mfma<IN2, OUTC><<<dim3(GRIDM, 2 * HO2 / 128), 256, 0, stream>>>(
        xb, IN, h1b, HO1, Wt2, bl2, br2, HO2,
        (size_t)NN * OUTC, xl2, xr2);
    gather2<<<NN, 192, 0, stream>>>(rowoff, csrsrc, xl2, xr2, att2, bias2,
                                    (float*)d_out);
}

// Round 15
// 254.140 us; speedup vs baseline: 1.4427x; 1.1492x over previous
//
#include <hip/hip_runtime.h>
#include <hip/hip_bf16.h>

#define NN 20000
#define EE 320000
#define IN 128
#define HID 64
#define OUTC 128
#define NH 3
#define NEG 0.15f
#define IN2 320
#define HO1 192   // NH*HID
#define HO2 384   // NH*OUTC
#define NB_SCAN 79   // ceil(NN/256)
#define GRIDM128 157 // ceil(NN/128)
#define LDA 72       // 64 + 8 pad (bank-spread)

typedef __hip_bfloat16 bf16;
typedef __attribute__((ext_vector_type(8))) short short8;  // 8 bf16 = 4 VGPR
typedef __attribute__((ext_vector_type(4))) float f32x4;   // MFMA C/D frag

__device__ __forceinline__ float bf2f(bf16 v) { return __bfloat162float(v); }
__device__ __forceinline__ bf16 f2bf(float v) { return __float2bfloat16(v); }
__device__ __forceinline__ float lrelu(float s) { return s > 0.f ? s : NEG * s; }
__device__ __forceinline__ float b2f(unsigned short u) {
    union { unsigned int i; float f; } c; c.i = ((unsigned int)u) << 16; return c.f;
}

// ---------------- CSR build (by dst) — proven rounds 4..14 ----------------
__global__ void k_count(const int* __restrict__ ei, int* __restrict__ cnt) {
    const int e = blockIdx.x * 256 + threadIdx.x;
    if (e < EE) atomicAdd(&cnt[ei[EE + e]], 1);
}

__global__ void k_scanA(const int* __restrict__ cnt, int* __restrict__ loc,
                        int* __restrict__ bsum) {
    __shared__ int sh[256];
    const int t = threadIdx.x;
    const int i = blockIdx.x * 256 + t;
    const int v = (i < NN) ? cnt[i] : 0;
    sh[t] = v; __syncthreads();
    for (int off = 1; off < 256; off <<= 1) {
        const int add = (t >= off) ? sh[t - off] : 0;
        __syncthreads();
        sh[t] += add; __syncthreads();
    }
    if (i < NN) loc[i] = sh[t];
    if (t == 255) bsum[blockIdx.x] = sh[255];
}

__global__ void k_scanB(int* __restrict__ bsum) {
    __shared__ int sh[128];
    const int t = threadIdx.x;
    const int v = (t < NB_SCAN) ? bsum[t] : 0;
    sh[t] = v; __syncthreads();
    for (int off = 1; off < 128; off <<= 1) {
        const int add = (t >= off) ? sh[t - off] : 0;
        __syncthreads();
        sh[t] += add; __syncthreads();
    }
    if (t < NB_SCAN) bsum[t] = sh[t] - v;
}

__global__ void k_scanC(const int* __restrict__ loc, const int* __restrict__ cnt,
                        const int* __restrict__ bsum, int* __restrict__ row_off,
                        int* __restrict__ fill) {
    const int i = blockIdx.x * 256 + threadIdx.x;
    if (i < NN) {
        const int ro = loc[i] - cnt[i] + bsum[blockIdx.x];
        row_off[i] = ro; fill[i] = ro;
    }
    if (i == 0) row_off[NN] = EE;
}

__global__ void k_scatter(const int* __restrict__ ei, int* __restrict__ fill,
                          int* __restrict__ csr_src) {
    const int e = blockIdx.x * 256 + threadIdx.x;
    if (e < EE) {
        const int p = atomicAdd(&fill[ei[EE + e]], 1);
        csr_src[p] = ei[e];
    }
}

// ---------------- pre-pass: bf16 casts / weight transpose ----------------
__global__ void k_a2x(const float* __restrict__ x, bf16* __restrict__ xb) {
    const int idx = blockIdx.x * 256 + threadIdx.x;
    if (idx < NN * IN) xb[idx] = f2bf(x[idx]);
}

__global__ void k_wt(const float* __restrict__ Wl, const float* __restrict__ Wr,
                     int K, int NO, bf16* __restrict__ Wt) {
    const int idx = blockIdx.x * 256 + threadIdx.x;
    if (idx >= 2 * NO * K) return;
    const int n = idx / K, k = idx - n * K;
    const float* W = (n < NO) ? Wl : Wr;
    const int nn = (n < NO) ? n : n - NO;
    Wt[idx] = f2bf(W[(size_t)k * NO + nn]);
}

// ---------------- MFMA GEMM v3: 128x128 tile, LDS-staged, BK=64 ----------------
// 4 waves 2x2; wave = 64x64 (4x4 16x16 frags). Staging: global->reg->LDS with
// next-step global loads issued before the MFMAs (latency hidden by compute).
// LDS rows padded 64->72 elems: frag ds_read_b128 lands 2 lanes/4-bank group (free).
template <int K, int CH>
__launch_bounds__(256)
__global__ void gemm_mfma(const bf16* __restrict__ A0, int As0,   // k < 128
                          const bf16* __restrict__ A1, int As1,   // k >= 128
                          const bf16* __restrict__ Wt,
                          const float* __restrict__ bl, const float* __restrict__ br,
                          int NO, size_t planeN,
                          bf16* __restrict__ outl, bf16* __restrict__ outr) {
    __shared__ bf16 Asm[128 * LDA];
    __shared__ bf16 Bsm[128 * LDA];
    const int tid = threadIdx.x;
    const int w = tid >> 6, lane = tid & 63;
    const int quad = lane >> 4, l15 = lane & 15;
    const int r0 = (w >> 1) * 64;          // wave row offset within tile
    const int c0 = (w & 1) * 64;           // wave col offset within tile
    const int m0 = blockIdx.x * 128;
    const int n0 = blockIdx.y * 128;

    // accumulators, bias-initialized
    f32x4 acc[4][4];
#pragma unroll
    for (int nt = 0; nt < 4; ++nt) {
        const int col = n0 + c0 + nt * 16 + l15;
        const float b = (col < NO) ? bl[col] : br[col - NO];
#pragma unroll
        for (int mt = 0; mt < 4; ++mt) acc[mt][nt] = (f32x4){b, b, b, b};
    }

    // staging segment map: s = q*256 + tid ; row = s>>3 ; koff = (s&7)*8
    int arow[4]; size_t boff[4]; int soff[4];
#pragma unroll
    for (int q = 0; q < 4; ++q) {
        const int s = q * 256 + tid;
        int r = m0 + (s >> 3); if (r >= NN) r = NN - 1;   // clamp (reads stay in ws)
        arow[q] = r;
        boff[q] = (size_t)(n0 + (s >> 3)) * K + (s & 7) * 8;
        soff[q] = (s >> 3) * LDA + (s & 7) * 8;
    }

    short8 pa[4], pb[4];
    // prologue: load K-step 0
#pragma unroll
    for (int q = 0; q < 4; ++q) {
        const int s = q * 256 + tid;
        pa[q] = *(const short8*)(A0 + (size_t)arow[q] * As0 + (s & 7) * 8);
        pb[q] = *(const short8*)(Wt + boff[q]);
    }

#pragma unroll
    for (int ks = 0; ks < K; ks += 64) {
        // commit staged regs to LDS
#pragma unroll
        for (int q = 0; q < 4; ++q) {
            *(short8*)&Asm[soff[q]] = pa[q];
            *(short8*)&Bsm[soff[q]] = pb[q];
        }
        __syncthreads();
        // issue next step's global loads (in flight during ds_read+MFMA)
        if (ks + 64 < K) {
            const int nks = ks + 64;
#pragma unroll
            for (int q = 0; q < 4; ++q) {
                const int s = q * 256 + tid;
                const bf16* ap = (K <= 128 || nks < 128)
                    ? (A0 + (size_t)arow[q] * As0 + nks + (s & 7) * 8)
                    : (A1 + (size_t)arow[q] * As1 + (nks - 128) + (s & 7) * 8);
                pa[q] = *(const short8*)ap;
                pb[q] = *(const short8*)(Wt + boff[q] + nks);
            }
        }
        // fragments from LDS + MFMAs
#pragma unroll
        for (int kq = 0; kq < 2; ++kq) {
            short8 af[4], bf[4];
#pragma unroll
            for (int mt = 0; mt < 4; ++mt)
                af[mt] = *(const short8*)&Asm[(r0 + mt * 16 + l15) * LDA + kq * 32 + quad * 8];
#pragma unroll
            for (int nt = 0; nt < 4; ++nt)
                bf[nt] = *(const short8*)&Bsm[(c0 + nt * 16 + l15) * LDA + kq * 32 + quad * 8];
#pragma unroll
            for (int mt = 0; mt < 4; ++mt)
#pragma unroll
                for (int nt = 0; nt < 4; ++nt)
                    acc[mt][nt] = __builtin_amdgcn_mfma_f32_16x16x32_bf16(af[mt], bf[nt], acc[mt][nt], 0, 0, 0);
        }
        __syncthreads();
    }

    // epilogue: per-head planar store (layout proven rounds 13/14)
#pragma unroll
    for (int mt = 0; mt < 4; ++mt)
#pragma unroll
    for (int nt = 0; nt < 4; ++nt) {
        const int col = n0 + c0 + nt * 16 + l15;
        const int cc = (col < NO) ? col : col - NO;
        bf16* o = (col < NO) ? outl : outr;
        const int h = cc / CH, c = cc - h * CH;
#pragma unroll
        for (int r = 0; r < 4; ++r) {
            const int row = m0 + r0 + mt * 16 + quad * 4 + r;
            if (row < NN) o[h * planeN + (size_t)row * CH + c] = f2bf(acc[mt][nt][r]);
        }
    }
}

// ---------------- gather1 (unchanged from round 14, proven) ----------------
__global__ void gather1(const int* __restrict__ row_off, const int* __restrict__ csr_src,
                        const bf16* __restrict__ xl, const bf16* __restrict__ xr,
                        const float* __restrict__ att, const float* __restrict__ bias,
                        bf16* __restrict__ h1) {
    const int i = blockIdx.x;
    const int w = threadIdx.x >> 6;      // head
    const int lane = threadIdx.x & 63;
    const int g = lane >> 3;             // group 0..7 (edge slot)
    const int t = lane & 7;              // channels 8t..8t+7
    const unsigned short* xlu = (const unsigned short*)xl + (size_t)w * NN * HID;
    const unsigned short* xru = (const unsigned short*)xr + (size_t)w * NN * HID;
    float rv[8], av[8];
    {
        const short8 ru = *(const short8*)(xru + (size_t)i * HID + 8 * t);
#pragma unroll
        for (int c = 0; c < 8; ++c) {
            rv[c] = b2f((unsigned short)ru[c]);
            av[c] = att[w * HID + 8 * t + c];
        }
    }
    float acc[8] = {0.f, 0.f, 0.f, 0.f, 0.f, 0.f, 0.f, 0.f};
    float den = 0.f;
    const int kb = row_off[i], ke = row_off[i + 1];
    for (int p0 = kb; p0 < ke; p0 += 8) {
        const int idx = p0 + g;
        const int j = csr_src[idx < ke ? idx : ke - 1];
        const short8 lu = *(const short8*)(xlu + (size_t)j * HID + 8 * t);
        float lv[8], p = 0.f;
#pragma unroll
        for (int c = 0; c < 8; ++c) {
            lv[c] = b2f((unsigned short)lu[c]);
            p += lrelu(lv[c] + rv[c]) * av[c];
        }
        p += __shfl_xor(p, 1, 64);
        p += __shfl_xor(p, 2, 64);
        p += __shfl_xor(p, 4, 64);
        const float ex = (idx < ke) ? __expf(p) : 0.f;
#pragma unroll
        for (int c = 0; c < 8; ++c) acc[c] += ex * lv[c];
        den += ex;
    }
    __shared__ float part[NH][8][HID];
    __shared__ float dsh[NH][8];
    *(f32x4*)&part[w][g][8 * t]     = (f32x4){acc[0], acc[1], acc[2], acc[3]};
    *(f32x4*)&part[w][g][8 * t + 4] = (f32x4){acc[4], acc[5], acc[6], acc[7]};
    if (t == 0) dsh[w][g] = den;
    __syncthreads();
    const int o = threadIdx.x;           // 0..191 = h*64+c
    const int hh = o >> 6, c = o & 63;
    float num = 0.f, dd = 0.f;
#pragma unroll
    for (int q = 0; q < 8; ++q) { num += part[hh][q][c]; dd += dsh[hh][q]; }
    const float v = num / (dd + 1e-16f) + bias[o];
    h1[(size_t)i * HO1 + o] = f2bf(v > 0.f ? v : 0.f);
}

// ---------------- gather2 (unchanged from round 14, proven) ----------------
__global__ void gather2(const int* __restrict__ row_off, const int* __restrict__ csr_src,
                        const bf16* __restrict__ xl2, const bf16* __restrict__ xr2,
                        const float* __restrict__ att2, const float* __restrict__ bias2,
                        float* __restrict__ out) {
    const int i = blockIdx.x;
    const int w = threadIdx.x >> 6;      // head
    const int lane = threadIdx.x & 63;
    const int g = lane >> 4;             // group 0..3 (edge slot)
    const int t = lane & 15;             // channels 8t..8t+7
    const unsigned short* xlu = (const unsigned short*)xl2 + (size_t)w * NN * OUTC;
    const unsigned short* xru = (const unsigned short*)xr2 + (size_t)w * NN * OUTC;
    float rv[8], av[8];
    {
        const short8 ru = *(const short8*)(xru + (size_t)i * OUTC + 8 * t);
#pragma unroll
        for (int c = 0; c < 8; ++c) {
            rv[c] = b2f((unsigned short)ru[c]);
            av[c] = att2[w * OUTC + 8 * t + c];
        }
    }
    float acc[8] = {0.f, 0.f, 0.f, 0.f, 0.f, 0.f, 0.f, 0.f};
    float den = 0.f;
    const int kb = row_off[i], ke = row_off[i + 1];
    for (int p0 = kb; p0 < ke; p0 += 4) {
        const int idx = p0 + g;
        const int j = csr_src[idx < ke ? idx : ke - 1];
        const short8 lu = *(const short8*)(xlu + (size_t)j * OUTC + 8 * t);
        float lv[8], p = 0.f;
#pragma unroll
        for (int c = 0; c < 8; ++c) {
            lv[c] = b2f((unsigned short)lu[c]);
            p += lrelu(lv[c] + rv[c]) * av[c];
        }
        p += __shfl_xor(p, 1, 64);
        p += __shfl_xor(p, 2, 64);
        p += __shfl_xor(p, 4, 64);
        p += __shfl_xor(p, 8, 64);
        const float ex = (idx < ke) ? __expf(p) : 0.f;
#pragma unroll
        for (int c = 0; c < 8; ++c) acc[c] += ex * lv[c];
        den += ex;
    }
    __shared__ float part[NH][4][OUTC];
    __shared__ float dsh[NH][4];
    *(f32x4*)&part[w][g][8 * t]     = (f32x4){acc[0], acc[1], acc[2], acc[3]};
    *(f32x4*)&part[w][g][8 * t + 4] = (f32x4){acc[4], acc[5], acc[6], acc[7]};
    if (t == 0) dsh[w][g] = den;
    __syncthreads();
    if (threadIdx.x < OUTC) {
        const int c = threadIdx.x;
        float v = 0.f;
#pragma unroll
        for (int hh = 0; hh < NH; ++hh) {
            float num = part[hh][0][c] + part[hh][1][c] + part[hh][2][c] + part[hh][3][c];
            float dd  = dsh[hh][0] + dsh[hh][1] + dsh[hh][2] + dsh[hh][3];
            v += num / (dd + 1e-16f);
        }
        v = v * (1.f / 3.f) + bias2[c];
        out[(size_t)i * OUTC + c] = v > 0.f ? v : 0.f;
    }
}

extern "C" void kernel_launch(void* const* d_in, const int* in_sizes, int n_in,
                              void* d_out, int out_size, void* d_ws, size_t ws_size,
                              hipStream_t stream) {
    const float* x    = (const float*)d_in[0];
    const float* Wl1  = (const float*)d_in[1];
    const float* bl1  = (const float*)d_in[2];
    const float* Wr1  = (const float*)d_in[3];
    const float* br1  = (const float*)d_in[4];
    const float* att1 = (const float*)d_in[5];
    const float* bias1= (const float*)d_in[6];
    const float* Wl2  = (const float*)d_in[7];
    const float* bl2  = (const float*)d_in[8];
    const float* Wr2  = (const float*)d_in[9];
    const float* br2  = (const float*)d_in[10];
    const float* att2 = (const float*)d_in[11];
    const float* bias2= (const float*)d_in[12];
    const int*   ei   = (const int*)d_in[13];

    char* ws = (char*)d_ws;
    // Pool layout (bytes), peak 45,713,936 — byte-identical to proven rounds 10-14:
    //  [0,         5,120,000)  xb   bf16 [N,128]
    //  [5.12e6,   12,800,000)  h1b  bf16 [N,192]
    //  [12.8e6,   20,480,000)  xl1 planar [3][N][64]  \ dead after gather1 ->
    //  [20.48e6,  28,160,000)  xr1 planar [3][N][64]  /  xl2 planar [3][N][128]
    //  [28.16e6,  43,520,000)  xr2 planar [3][N][128]
    //  [43.52e6,  45,124,104)  CSR: cnt/fill/loc/bsum/rowoff/csrsrc
    //  [45,124,112, 45,222,416)  Wt1 bf16 [384][128]
    //  [45,222,416, 45,713,936)  Wt2 bf16 [768][320]
    bf16*  xb     = (bf16*)(ws);
    bf16*  h1b    = (bf16*)(ws + 5120000);
    bf16*  xl1    = (bf16*)(ws + 12800000);
    bf16*  xr1    = (bf16*)(ws + 20480000);
    bf16*  xl2    = (bf16*)(ws + 12800000);   // alias: xl1/xr1 dead after gather1
    bf16*  xr2    = (bf16*)(ws + 28160000);
    int*   cnt    = (int*)(ws + 43520000);
    int*   fill   = (int*)(ws + 43600000);
    int*   loc    = (int*)(ws + 43680000);
    int*   bsum   = (int*)(ws + 43760000);
    int*   rowoff = (int*)(ws + 43764096);
    int*   csrsrc = (int*)(ws + 43844104);
    bf16*  Wt1    = (bf16*)(ws + 45124112);
    bf16*  Wt2    = (bf16*)(ws + 45222416);

    // ---- pre-pass: casts + weight transposes ----
    k_a2x<<<(NN * IN + 255) / 256, 256, 0, stream>>>(x, xb);
    k_wt<<<(HO2 * IN + 255) / 256, 256, 0, stream>>>(Wl1, Wr1, IN, HO1, Wt1);
    k_wt<<<(2 * HO2 * IN2 + 255) / 256, 256, 0, stream>>>(Wl2, Wr2, IN2, HO2, Wt2);

    // ---- CSR build ----
    hipMemsetAsync(cnt, 0, NN * sizeof(int), stream);
    k_count<<<(EE + 255) / 256, 256, 0, stream>>>(ei, cnt);
    k_scanA<<<NB_SCAN, 256, 0, stream>>>(cnt, loc, bsum);
    k_scanB<<<1, 128, 0, stream>>>(bsum);
    k_scanC<<<NB_SCAN, 256, 0, stream>>>(loc, cnt, bsum, rowoff, fill);
    k_scatter<<<(EE + 255) / 256, 256, 0, stream>>>(ei, fill, csrsrc);

    // ---- layer 1 ----
    gemm_mfma<IN, HID><<<dim3(GRIDM128, HO2 / 128), 256, 0, stream>>>(
        xb, IN, (const bf16*)nullptr, 0, Wt1, bl1, br1, HO1,
        (size_t)NN * HID, xl1, xr1);
    gather1<<<NN, 192, 0, stream>>>(rowoff, csrsrc, xl1, xr1, att1, bias1, h1b);

    // ---- layer 2 ----
    gemm_mfma<IN2, OUTC><<<dim3(GRIDM128, 2 * HO2 / 128), 256, 0, stream>>>(
        xb, IN, h1b, HO1, Wt2, bl2, br2, HO2,
        (size_t)NN * OUTC, xl2, xr2);
    gather2<<<NN, 192, 0, stream>>>(rowoff, csrsrc, xl2, xr2, att2, bias2,
                                    (float*)d_out);
}

// Round 16
// 248.619 us; speedup vs baseline: 1.4747x; 1.0222x over previous
//
#include <hip/hip_runtime.h>
#include <hip/hip_bf16.h>

#define NN 20000
#define EE 320000
#define IN 128
#define HID 64
#define OUTC 128
#define NH 3
#define NEG 0.15f
#define IN2 320
#define HO1 192   // NH*HID
#define HO2 384   // NH*OUTC
#define NB_SCAN 79   // ceil(NN/256)
#define GRIDM128 157 // ceil(NN/128)
#define LDA 72       // 64 + 8 pad (bank-spread)

typedef __hip_bfloat16 bf16;
typedef __attribute__((ext_vector_type(8))) short short8;  // 8 bf16 = 4 VGPR
typedef __attribute__((ext_vector_type(4))) float f32x4;   // MFMA C/D frag

__device__ __forceinline__ float bf2f(bf16 v) { return __bfloat162float(v); }
__device__ __forceinline__ bf16 f2bf(float v) { return __float2bfloat16(v); }
__device__ __forceinline__ float lrelu(float s) { return fmaxf(s, NEG * s); }  // == s>0?s:0.15s
__device__ __forceinline__ float lo16(unsigned int d) {
    union { unsigned int u; float f; } c; c.u = d << 16; return c.f;
}
__device__ __forceinline__ float hi16(unsigned int d) {
    union { unsigned int u; float f; } c; c.u = d & 0xffff0000u; return c.f;
}

// ---------------- CSR build (by dst) — proven rounds 4..15 ----------------
__global__ void k_count(const int* __restrict__ ei, int* __restrict__ cnt) {
    const int e = blockIdx.x * 256 + threadIdx.x;
    if (e < EE) atomicAdd(&cnt[ei[EE + e]], 1);
}

__global__ void k_scanA(const int* __restrict__ cnt, int* __restrict__ loc,
                        int* __restrict__ bsum) {
    __shared__ int sh[256];
    const int t = threadIdx.x;
    const int i = blockIdx.x * 256 + t;
    const int v = (i < NN) ? cnt[i] : 0;
    sh[t] = v; __syncthreads();
    for (int off = 1; off < 256; off <<= 1) {
        const int add = (t >= off) ? sh[t - off] : 0;
        __syncthreads();
        sh[t] += add; __syncthreads();
    }
    if (i < NN) loc[i] = sh[t];
    if (t == 255) bsum[blockIdx.x] = sh[255];
}

__global__ void k_scanB(int* __restrict__ bsum) {
    __shared__ int sh[128];
    const int t = threadIdx.x;
    const int v = (t < NB_SCAN) ? bsum[t] : 0;
    sh[t] = v; __syncthreads();
    for (int off = 1; off < 128; off <<= 1) {
        const int add = (t >= off) ? sh[t - off] : 0;
        __syncthreads();
        sh[t] += add; __syncthreads();
    }
    if (t < NB_SCAN) bsum[t] = sh[t] - v;
}

__global__ void k_scanC(const int* __restrict__ loc, const int* __restrict__ cnt,
                        const int* __restrict__ bsum, int* __restrict__ row_off,
                        int* __restrict__ fill) {
    const int i = blockIdx.x * 256 + threadIdx.x;
    if (i < NN) {
        const int ro = loc[i] - cnt[i] + bsum[blockIdx.x];
        row_off[i] = ro; fill[i] = ro;
    }
    if (i == 0) row_off[NN] = EE;
}

__global__ void k_scatter(const int* __restrict__ ei, int* __restrict__ fill,
                          int* __restrict__ csr_src) {
    const int e = blockIdx.x * 256 + threadIdx.x;
    if (e < EE) {
        const int p = atomicAdd(&fill[ei[EE + e]], 1);
        csr_src[p] = ei[e];
    }
}

// ---------------- pre-pass: bf16 casts / weight transpose ----------------
__global__ void k_a2x(const float* __restrict__ x, bf16* __restrict__ xb) {
    const int idx = blockIdx.x * 256 + threadIdx.x;
    if (idx < NN * IN) xb[idx] = f2bf(x[idx]);
}

__global__ void k_wt(const float* __restrict__ Wl, const float* __restrict__ Wr,
                     int K, int NO, bf16* __restrict__ Wt) {
    const int idx = blockIdx.x * 256 + threadIdx.x;
    if (idx >= 2 * NO * K) return;
    const int n = idx / K, k = idx - n * K;
    const float* W = (n < NO) ? Wl : Wr;
    const int nn = (n < NO) ? n : n - NO;
    Wt[idx] = f2bf(W[(size_t)k * NO + nn]);
}

// ---------------- MFMA GEMM v3: 128x128 tile, LDS-staged, BK=64 (round 15) -----
template <int K, int CH>
__launch_bounds__(256)
__global__ void gemm_mfma(const bf16* __restrict__ A0, int As0,   // k < 128
                          const bf16* __restrict__ A1, int As1,   // k >= 128
                          const bf16* __restrict__ Wt,
                          const float* __restrict__ bl, const float* __restrict__ br,
                          int NO, size_t planeN,
                          bf16* __restrict__ outl, bf16* __restrict__ outr) {
    __shared__ bf16 Asm[128 * LDA];
    __shared__ bf16 Bsm[128 * LDA];
    const int tid = threadIdx.x;
    const int w = tid >> 6, lane = tid & 63;
    const int quad = lane >> 4, l15 = lane & 15;
    const int r0 = (w >> 1) * 64;
    const int c0 = (w & 1) * 64;
    const int m0 = blockIdx.x * 128;
    const int n0 = blockIdx.y * 128;

    f32x4 acc[4][4];
#pragma unroll
    for (int nt = 0; nt < 4; ++nt) {
        const int col = n0 + c0 + nt * 16 + l15;
        const float b = (col < NO) ? bl[col] : br[col - NO];
#pragma unroll
        for (int mt = 0; mt < 4; ++mt) acc[mt][nt] = (f32x4){b, b, b, b};
    }

    int arow[4]; size_t boff[4]; int soff[4];
#pragma unroll
    for (int q = 0; q < 4; ++q) {
        const int s = q * 256 + tid;
        int r = m0 + (s >> 3); if (r >= NN) r = NN - 1;
        arow[q] = r;
        boff[q] = (size_t)(n0 + (s >> 3)) * K + (s & 7) * 8;
        soff[q] = (s >> 3) * LDA + (s & 7) * 8;
    }

    short8 pa[4], pb[4];
#pragma unroll
    for (int q = 0; q < 4; ++q) {
        const int s = q * 256 + tid;
        pa[q] = *(const short8*)(A0 + (size_t)arow[q] * As0 + (s & 7) * 8);
        pb[q] = *(const short8*)(Wt + boff[q]);
    }

#pragma unroll
    for (int ks = 0; ks < K; ks += 64) {
#pragma unroll
        for (int q = 0; q < 4; ++q) {
            *(short8*)&Asm[soff[q]] = pa[q];
            *(short8*)&Bsm[soff[q]] = pb[q];
        }
        __syncthreads();
        if (ks + 64 < K) {
            const int nks = ks + 64;
#pragma unroll
            for (int q = 0; q < 4; ++q) {
                const int s = q * 256 + tid;
                const bf16* ap = (K <= 128 || nks < 128)
                    ? (A0 + (size_t)arow[q] * As0 + nks + (s & 7) * 8)
                    : (A1 + (size_t)arow[q] * As1 + (nks - 128) + (s & 7) * 8);
                pa[q] = *(const short8*)ap;
                pb[q] = *(const short8*)(Wt + boff[q] + nks);
            }
        }
#pragma unroll
        for (int kq = 0; kq < 2; ++kq) {
            short8 af[4], bf[4];
#pragma unroll
            for (int mt = 0; mt < 4; ++mt)
                af[mt] = *(const short8*)&Asm[(r0 + mt * 16 + l15) * LDA + kq * 32 + quad * 8];
#pragma unroll
            for (int nt = 0; nt < 4; ++nt)
                bf[nt] = *(const short8*)&Bsm[(c0 + nt * 16 + l15) * LDA + kq * 32 + quad * 8];
#pragma unroll
            for (int mt = 0; mt < 4; ++mt)
#pragma unroll
                for (int nt = 0; nt < 4; ++nt)
                    acc[mt][nt] = __builtin_amdgcn_mfma_f32_16x16x32_bf16(af[mt], bf[nt], acc[mt][nt], 0, 0, 0);
        }
        __syncthreads();
    }

#pragma unroll
    for (int mt = 0; mt < 4; ++mt)
#pragma unroll
    for (int nt = 0; nt < 4; ++nt) {
        const int col = n0 + c0 + nt * 16 + l15;
        const int cc = (col < NO) ? col : col - NO;
        bf16* o = (col < NO) ? outl : outr;
        const int h = cc / CH, c = cc - h * CH;
#pragma unroll
        for (int r = 0; r < 4; ++r) {
            const int row = m0 + r0 + mt * 16 + quad * 4 + r;
            if (row < NN) o[h * planeN + (size_t)row * CH + c] = f2bf(acc[mt][nt][r]);
        }
    }
}

// ---------------- gather1: 8-lane group/edge; dword-cvt + max-lrelu ----------
__global__ void gather1(const int* __restrict__ row_off, const int* __restrict__ csr_src,
                        const bf16* __restrict__ xl, const bf16* __restrict__ xr,
                        const float* __restrict__ att, const float* __restrict__ bias,
                        bf16* __restrict__ h1) {
    const int i = blockIdx.x;
    const int w = threadIdx.x >> 6;      // head
    const int lane = threadIdx.x & 63;
    const int g = lane >> 3;             // group 0..7 (edge slot)
    const int t = lane & 7;              // channels 8t..8t+7
    const unsigned short* xlu = (const unsigned short*)xl + (size_t)w * NN * HID;
    const unsigned short* xru = (const unsigned short*)xr + (size_t)w * NN * HID;
    float rv[8], av[8];
    {
        const uint4 ru = *(const uint4*)(xru + (size_t)i * HID + 8 * t);
        rv[0] = lo16(ru.x); rv[1] = hi16(ru.x);
        rv[2] = lo16(ru.y); rv[3] = hi16(ru.y);
        rv[4] = lo16(ru.z); rv[5] = hi16(ru.z);
        rv[6] = lo16(ru.w); rv[7] = hi16(ru.w);
#pragma unroll
        for (int c = 0; c < 8; ++c) av[c] = att[w * HID + 8 * t + c];
    }
    float acc[8] = {0.f, 0.f, 0.f, 0.f, 0.f, 0.f, 0.f, 0.f};
    float den = 0.f;
    const int kb = row_off[i], ke = row_off[i + 1];
    for (int p0 = kb; p0 < ke; p0 += 8) {
        const int idx = p0 + g;
        const int j = csr_src[idx < ke ? idx : ke - 1];
        const uint4 lu = *(const uint4*)(xlu + (size_t)j * HID + 8 * t);
        float lv[8];
        lv[0] = lo16(lu.x); lv[1] = hi16(lu.x);
        lv[2] = lo16(lu.y); lv[3] = hi16(lu.y);
        lv[4] = lo16(lu.z); lv[5] = hi16(lu.z);
        lv[6] = lo16(lu.w); lv[7] = hi16(lu.w);
        float p = 0.f;
#pragma unroll
        for (int c = 0; c < 8; ++c)
            p = fmaf(lrelu(lv[c] + rv[c]), av[c], p);
        p += __shfl_xor(p, 1, 64);
        p += __shfl_xor(p, 2, 64);
        p += __shfl_xor(p, 4, 64);
        const float ex = (idx < ke) ? __expf(p) : 0.f;   // |logit|<~8: fp32-safe
#pragma unroll
        for (int c = 0; c < 8; ++c) acc[c] = fmaf(ex, lv[c], acc[c]);
        den += ex;
    }
    __shared__ float part[NH][8][HID];
    __shared__ float dsh[NH][8];
    *(f32x4*)&part[w][g][8 * t]     = (f32x4){acc[0], acc[1], acc[2], acc[3]};
    *(f32x4*)&part[w][g][8 * t + 4] = (f32x4){acc[4], acc[5], acc[6], acc[7]};
    if (t == 0) dsh[w][g] = den;
    __syncthreads();
    const int o = threadIdx.x;           // 0..191 = h*64+c
    const int hh = o >> 6, c = o & 63;
    float num = 0.f, dd = 0.f;
#pragma unroll
    for (int q = 0; q < 8; ++q) { num += part[hh][q][c]; dd += dsh[hh][q]; }
    const float v = num / (dd + 1e-16f) + bias[o];
    h1[(size_t)i * HO1 + o] = f2bf(v > 0.f ? v : 0.f);
}

// ---------------- gather2: 16-lane group/edge; dword-cvt + max-lrelu ---------
__global__ void gather2(const int* __restrict__ row_off, const int* __restrict__ csr_src,
                        const bf16* __restrict__ xl2, const bf16* __restrict__ xr2,
                        const float* __restrict__ att2, const float* __restrict__ bias2,
                        float* __restrict__ out) {
    const int i = blockIdx.x;
    const int w = threadIdx.x >> 6;      // head
    const int lane = threadIdx.x & 63;
    const int g = lane >> 4;             // group 0..3 (edge slot)
    const int t = lane & 15;             // channels 8t..8t+7
    const unsigned short* xlu = (const unsigned short*)xl2 + (size_t)w * NN * OUTC;
    const unsigned short* xru = (const unsigned short*)xr2 + (size_t)w * NN * OUTC;
    float rv[8], av[8];
    {
        const uint4 ru = *(const uint4*)(xru + (size_t)i * OUTC + 8 * t);
        rv[0] = lo16(ru.x); rv[1] = hi16(ru.x);
        rv[2] = lo16(ru.y); rv[3] = hi16(ru.y);
        rv[4] = lo16(ru.z); rv[5] = hi16(ru.z);
        rv[6] = lo16(ru.w); rv[7] = hi16(ru.w);
#pragma unroll
        for (int c = 0; c < 8; ++c) av[c] = att2[w * OUTC + 8 * t + c];
    }
    float acc[8] = {0.f, 0.f, 0.f, 0.f, 0.f, 0.f, 0.f, 0.f};
    float den = 0.f;
    const int kb = row_off[i], ke = row_off[i + 1];
    for (int p0 = kb; p0 < ke; p0 += 4) {
        const int idx = p0 + g;
        const int j = csr_src[idx < ke ? idx : ke - 1];
        const uint4 lu = *(const uint4*)(xlu + (size_t)j * OUTC + 8 * t);
        float lv[8];
        lv[0] = lo16(lu.x); lv[1] = hi16(lu.x);
        lv[2] = lo16(lu.y); lv[3] = hi16(lu.y);
        lv[4] = lo16(lu.z); lv[5] = hi16(lu.z);
        lv[6] = lo16(lu.w); lv[7] = hi16(lu.w);
        float p = 0.f;
#pragma unroll
        for (int c = 0; c < 8; ++c)
            p = fmaf(lrelu(lv[c] + rv[c]), av[c], p);
        p += __shfl_xor(p, 1, 64);
        p += __shfl_xor(p, 2, 64);
        p += __shfl_xor(p, 4, 64);
        p += __shfl_xor(p, 8, 64);
        const float ex = (idx < ke) ? __expf(p) : 0.f;
#pragma unroll
        for (int c = 0; c < 8; ++c) acc[c] = fmaf(ex, lv[c], acc[c]);
        den += ex;
    }
    __shared__ float part[NH][4][OUTC];
    __shared__ float dsh[NH][4];
    *(f32x4*)&part[w][g][8 * t]     = (f32x4){acc[0], acc[1], acc[2], acc[3]};
    *(f32x4*)&part[w][g][8 * t + 4] = (f32x4){acc[4], acc[5], acc[6], acc[7]};
    if (t == 0) dsh[w][g] = den;
    __syncthreads();
    if (threadIdx.x < OUTC) {
        const int c = threadIdx.x;
        float v = 0.f;
#pragma unroll
        for (int hh = 0; hh < NH; ++hh) {
            float num = part[hh][0][c] + part[hh][1][c] + part[hh][2][c] + part[hh][3][c];
            float dd  = dsh[hh][0] + dsh[hh][1] + dsh[hh][2] + dsh[hh][3];
            v += num / (dd + 1e-16f);
        }
        v = v * (1.f / 3.f) + bias2[c];
        out[(size_t)i * OUTC + c] = v > 0.f ? v : 0.f;
    }
}

extern "C" void kernel_launch(void* const* d_in, const int* in_sizes, int n_in,
                              void* d_out, int out_size, void* d_ws, size_t ws_size,
                              hipStream_t stream) {
    const float* x    = (const float*)d_in[0];
    const float* Wl1  = (const float*)d_in[1];
    const float* bl1  = (const float*)d_in[2];
    const float* Wr1  = (const float*)d_in[3];
    const float* br1  = (const float*)d_in[4];
    const float* att1 = (const float*)d_in[5];
    const float* bias1= (const float*)d_in[6];
    const float* Wl2  = (const float*)d_in[7];
    const float* bl2  = (const float*)d_in[8];
    const float* Wr2  = (const float*)d_in[9];
    const float* br2  = (const float*)d_in[10];
    const float* att2 = (const float*)d_in[11];
    const float* bias2= (const float*)d_in[12];
    const int*   ei   = (const int*)d_in[13];

    char* ws = (char*)d_ws;
    // Pool layout (bytes), peak 45,713,936 — byte-identical to proven rounds 10-15:
    //  [0,         5,120,000)  xb   bf16 [N,128]
    //  [5.12e6,   12,800,000)  h1b  bf16 [N,192]
    //  [12.8e6,   20,480,000)  xl1 planar [3][N][64]  \ dead after gather1 ->
    //  [20.48e6,  28,160,000)  xr1 planar [3][N][64]  /  xl2 planar [3][N][128]
    //  [28.16e6,  43,520,000)  xr2 planar [3][N][128]
    //  [43.52e6,  45,124,104)  CSR: cnt/fill/loc/bsum/rowoff/csrsrc
    //  [45,124,112, 45,222,416)  Wt1 bf16 [384][128]
    //  [45,222,416, 45,713,936)  Wt2 bf16 [768][320]
    bf16*  xb     = (bf16*)(ws);
    bf16*  h1b    = (bf16*)(ws + 5120000);
    bf16*  xl1    = (bf16*)(ws + 12800000);
    bf16*  xr1    = (bf16*)(ws + 20480000);
    bf16*  xl2    = (bf16*)(ws + 12800000);   // alias: xl1/xr1 dead after gather1
    bf16*  xr2    = (bf16*)(ws + 28160000);
    int*   cnt    = (int*)(ws + 43520000);
    int*   fill   = (int*)(ws + 43600000);
    int*   loc    = (int*)(ws + 43680000);
    int*   bsum   = (int*)(ws + 43760000);
    int*   rowoff = (int*)(ws + 43764096);
    int*   csrsrc = (int*)(ws + 43844104);
    bf16*  Wt1    = (bf16*)(ws + 45124112);
    bf16*  Wt2    = (bf16*)(ws + 45222416);

    // ---- pre-pass: casts + weight transposes ----
    k_a2x<<<(NN * IN + 255) / 256, 256, 0, stream>>>(x, xb);
    k_wt<<<(HO2 * IN + 255) / 256, 256, 0, stream>>>(Wl1, Wr1, IN, HO1, Wt1);
    k_wt<<<(2 * HO2 * IN2 + 255) / 256, 256, 0, stream>>>(Wl2, Wr2, IN2, HO2, Wt2);

    // ---- CSR build ----
    hipMemsetAsync(cnt, 0, NN * sizeof(int), stream);
    k_count<<<(EE + 255) / 256, 256, 0, stream>>>(ei, cnt);
    k_scanA<<<NB_SCAN, 256, 0, stream>>>(cnt, loc, bsum);
    k_scanB<<<1, 128, 0, stream>>>(bsum);
    k_scanC<<<NB_SCAN, 256, 0, stream>>>(loc, cnt, bsum, rowoff, fill);
    k_scatter<<<(EE + 255) / 256, 256, 0, stream>>>(ei, fill, csrsrc);

    // ---- layer 1 ----
    gemm_mfma<IN, HID><<<dim3(GRIDM128, HO2 / 128), 256, 0, stream>>>(
        xb, IN, (const bf16*)nullptr, 0, Wt1, bl1, br1, HO1,
        (size_t)NN * HID, xl1, xr1);
    gather1<<<NN, 192, 0, stream>>>(rowoff, csrsrc, xl1, xr1, att1, bias1, h1b);

    // ---- layer 2 ----
    gemm_mfma<IN2, OUTC><<<dim3(GRIDM128, 2 * HO2 / 128), 256, 0, stream>>>(
        xb, IN, h1b, HO1, Wt2, bl2, br2, HO2,
        (size_t)NN * OUTC, xl2, xr2);
    gather2<<<NN, 192, 0, stream>>>(rowoff, csrsrc, xl2, xr2, att2, bias2,
                                    (float*)d_out);
}